// Round 3
// baseline (473.624 us; speedup 1.0000x reference)
//
#include <hip/hip_runtime.h>

#define NN 100000
#define EE 500000
#define FIN 64
#define HH 128
#define BN_EPS 1e-5f
#define NB ((NN + 255) / 256)   // 391 scan blocks

// ---------------- CSR build ----------------

__global__ __launch_bounds__(256) void hist_kernel(const int* __restrict__ dst,
                                                   int* __restrict__ deg) {
    int e = blockIdx.x * 256 + threadIdx.x;
    if (e < EE) atomicAdd(&deg[dst[e]], 1);
}

__global__ __launch_bounds__(256) void dinv_kernel(const int* __restrict__ deg,
                                                   float* __restrict__ dinv) {
    int i = blockIdx.x * 256 + threadIdx.x;
    if (i < NN) dinv[i] = rsqrtf((float)deg[i] + 1.0f);
}

__global__ __launch_bounds__(256) void scan1_kernel(const int* __restrict__ deg,
                                                    int* __restrict__ rowstart,
                                                    int* __restrict__ blksum) {
    __shared__ int s[256];
    int t = threadIdx.x;
    int i = blockIdx.x * 256 + t;
    int v = (i < NN) ? deg[i] : 0;
    s[t] = v;
    __syncthreads();
    #pragma unroll
    for (int off = 1; off < 256; off <<= 1) {
        int add = (t >= off) ? s[t - off] : 0;
        __syncthreads();
        s[t] += add;
        __syncthreads();
    }
    if (i < NN) rowstart[i] = s[t] - v;
    if (t == 255) blksum[blockIdx.x] = s[255];
}

__global__ __launch_bounds__(512) void scan2_kernel(int* __restrict__ blksum) {
    __shared__ int s[512];
    int t = threadIdx.x;
    int v = (t < NB) ? blksum[t] : 0;
    s[t] = v;
    __syncthreads();
    #pragma unroll
    for (int off = 1; off < 512; off <<= 1) {
        int add = (t >= off) ? s[t - off] : 0;
        __syncthreads();
        s[t] += add;
        __syncthreads();
    }
    if (t < NB) blksum[t] = s[t] - v;
}

__global__ __launch_bounds__(256) void scan3_kernel(int* __restrict__ rowstart,
                                                    const int* __restrict__ blksum,
                                                    int* __restrict__ cursor) {
    int i = blockIdx.x * 256 + threadIdx.x;
    if (i < NN) {
        int r = rowstart[i] + blksum[i >> 8];
        rowstart[i] = r;
        cursor[i] = r;
    }
    if (i == 0) rowstart[NN] = EE;
}

__global__ __launch_bounds__(256) void fill_kernel(const int* __restrict__ src,
                                                   const int* __restrict__ dst,
                                                   const float* __restrict__ dinv,
                                                   int* __restrict__ cursor,
                                                   int2* __restrict__ csr) {
    int e = blockIdx.x * 256 + threadIdx.x;
    if (e >= EE) return;
    int s = src[e];
    int d = dst[e];
    float nm = dinv[s] * dinv[d];
    int pos = atomicAdd(&cursor[d], 1);
    csr[pos] = make_int2(s, __float_as_int(nm));
}

// ---------------- gather aggregation ----------------

__global__ __launch_bounds__(256) void agg128_kernel(const float* __restrict__ x,
                                                     const int2* __restrict__ csr,
                                                     const int* __restrict__ rowstart,
                                                     const float* __restrict__ dinv,
                                                     float* __restrict__ out) {
    int gid = blockIdx.x * 4 + (threadIdx.x >> 6);
    int lane = threadIdx.x & 63;
    if (gid >= NN) return;
    float sn = dinv[gid];
    sn *= sn;
    float2 acc = *(const float2*)&x[(size_t)gid * HH + lane * 2];
    acc.x *= sn; acc.y *= sn;
    int e0 = rowstart[gid], e1 = rowstart[gid + 1];
    for (int e = e0; e < e1; e++) {
        int2 ed = csr[e];
        float w = __int_as_float(ed.y);
        float2 xs = *(const float2*)&x[(size_t)ed.x * HH + lane * 2];
        acc.x += xs.x * w;
        acc.y += xs.y * w;
    }
    *(float2*)&out[(size_t)gid * HH + lane * 2] = acc;
}

__global__ __launch_bounds__(256) void agg64_kernel(const float* __restrict__ x,
                                                    const int2* __restrict__ csr,
                                                    const int* __restrict__ rowstart,
                                                    const float* __restrict__ dinv,
                                                    float* __restrict__ out) {
    int gid = blockIdx.x * 8 + (threadIdx.x >> 5);
    int lane = threadIdx.x & 31;
    if (gid >= NN) return;
    float sn = dinv[gid];
    sn *= sn;
    float2 acc = *(const float2*)&x[(size_t)gid * FIN + lane * 2];
    acc.x *= sn; acc.y *= sn;
    int e0 = rowstart[gid], e1 = rowstart[gid + 1];
    for (int e = e0; e < e1; e++) {
        int2 ed = csr[e];
        float w = __int_as_float(ed.y);
        float2 xs = *(const float2*)&x[(size_t)ed.x * FIN + lane * 2];
        acc.x += xs.x * w;
        acc.y += xs.y * w;
    }
    *(float2*)&out[(size_t)gid * FIN + lane * 2] = acc;
}

// ---------------- tiled GEMM + bias + BN(eval) + ReLU (+ residual) ----------------
// BM=128 rows/block, BN=128 (all cols), Kc=32. 256 threads, 8x8 reg tile each.

template<int K>
__global__ __launch_bounds__(256, 2) void gemm_bn_relu(const float* __restrict__ A,
                                                       const float* __restrict__ W,
                                                       const float* __restrict__ bias,
                                                       const float* __restrict__ g,
                                                       const float* __restrict__ be,
                                                       const float* __restrict__ m,
                                                       const float* __restrict__ v,
                                                       const float* __restrict__ res,
                                                       float* __restrict__ out) {
    __shared__ float As[128][36];   // stride 36: 16B-aligned, bank-uniform
    __shared__ float Ws[32][128];

    int tid = threadIdx.x;
    int tx = tid & 15;
    int ty = tid >> 4;
    int row0 = blockIdx.x * 128;

    // staging task decomposition
    int a_kg  = tid & 7;          // k-group (4 floats)
    int a_row = tid >> 3;         // +t*32
    int w_n4  = tid & 31;         // col-group (4 floats)
    int w_kk  = tid >> 5;         // +t*8

    float4 regA[4], regW[4];

    // prefetch tile 0
    #pragma unroll
    for (int t = 0; t < 4; t++) {
        int row = t * 32 + a_row;
        int gr = row0 + row; if (gr >= NN) gr = NN - 1;
        regA[t] = *(const float4*)&A[(size_t)gr * K + a_kg * 4];
        int kk = t * 8 + w_kk;
        regW[t] = *(const float4*)&W[(size_t)kk * HH + w_n4 * 4];
    }

    float acc[8][8];
    #pragma unroll
    for (int ri = 0; ri < 8; ri++)
        #pragma unroll
        for (int ci = 0; ci < 8; ci++) acc[ri][ci] = 0.0f;

    for (int kc = 0; kc < K; kc += 32) {
        __syncthreads();   // previous tile's reads done
        #pragma unroll
        for (int t = 0; t < 4; t++) {
            *(float4*)&As[t * 32 + a_row][a_kg * 4] = regA[t];
            *(float4*)&Ws[t * 8 + w_kk][w_n4 * 4]   = regW[t];
        }
        if (kc + 32 < K) {
            int kc2 = kc + 32;
            #pragma unroll
            for (int t = 0; t < 4; t++) {
                int row = t * 32 + a_row;
                int gr = row0 + row; if (gr >= NN) gr = NN - 1;
                regA[t] = *(const float4*)&A[(size_t)gr * K + kc2 + a_kg * 4];
                int kk = t * 8 + w_kk;
                regW[t] = *(const float4*)&W[(size_t)(kc2 + kk) * HH + w_n4 * 4];
            }
        }
        __syncthreads();   // LDS ready

        #pragma unroll
        for (int kt = 0; kt < 8; kt++) {
            float4 a[8], b[8];
            #pragma unroll
            for (int r = 0; r < 4; r++) {
                a[r]     = *(const float4*)&As[ty * 4 + r][kt * 4];
                a[r + 4] = *(const float4*)&As[64 + ty * 4 + r][kt * 4];
            }
            #pragma unroll
            for (int j = 0; j < 4; j++) {
                b[j]     = *(const float4*)&Ws[kt * 4 + j][tx * 4];
                b[j + 4] = *(const float4*)&Ws[kt * 4 + j][64 + tx * 4];
            }
            #pragma unroll
            for (int kk = 0; kk < 4; kk++) {
                float av[8], bv[8];
                #pragma unroll
                for (int r = 0; r < 8; r++) av[r] = ((const float*)&a[r])[kk];
                #pragma unroll
                for (int c = 0; c < 4; c++) {
                    bv[c]     = ((const float*)&b[kk])[c];
                    bv[c + 4] = ((const float*)&b[kk + 4])[c];
                }
                #pragma unroll
                for (int r = 0; r < 8; r++)
                    #pragma unroll
                    for (int c = 0; c < 8; c++)
                        acc[r][c] += av[r] * bv[c];
            }
        }
    }

    // epilogue: BN scale/shift per col
    float sc[8], sh[8];
    #pragma unroll
    for (int c = 0; c < 8; c++) {
        int col = (c < 4) ? (tx * 4 + c) : (64 + tx * 4 + c - 4);
        float s = g[col] * rsqrtf(v[col] + BN_EPS);
        sc[c] = s;
        sh[c] = (bias[col] - m[col]) * s + be[col];
    }
    #pragma unroll
    for (int r = 0; r < 8; r++) {
        int row = row0 + ((r < 4) ? (ty * 4 + r) : (64 + ty * 4 + r - 4));
        if (row >= NN) continue;
        float o[8];
        #pragma unroll
        for (int c = 0; c < 8; c++) {
            float val = acc[r][c] * sc[c] + sh[c];
            val = fmaxf(val, 0.0f);
            o[c] = val;
        }
        if (res) {
            #pragma unroll
            for (int c = 0; c < 8; c++) {
                int col = (c < 4) ? (tx * 4 + c) : (64 + tx * 4 + c - 4);
                o[c] += res[(size_t)row * HH + col];
            }
        }
        *(float4*)&out[(size_t)row * HH + tx * 4]      = make_float4(o[0], o[1], o[2], o[3]);
        *(float4*)&out[(size_t)row * HH + 64 + tx * 4] = make_float4(o[4], o[5], o[6], o[7]);
    }
}

// ---------------- layer 4: z = x3 @ W4 (128 -> 1) ----------------

__global__ __launch_bounds__(256) void gemv_kernel(const float* __restrict__ x3,
                                                   const float* __restrict__ W4,
                                                   float* __restrict__ z) {
    int gtid = blockIdx.x * 256 + threadIdx.x;
    int row = gtid >> 6;
    int lane = gtid & 63;
    if (row >= NN) return;
    float2 xv = *(const float2*)&x3[(size_t)row * HH + lane * 2];
    float2 wv = *(const float2*)&W4[lane * 2];
    float s = xv.x * wv.x + xv.y * wv.y;
    #pragma unroll
    for (int off = 32; off; off >>= 1) s += __shfl_xor(s, off, 64);
    if (lane == 0) z[row] = s;
}

__global__ __launch_bounds__(256) void final_kernel(const float* __restrict__ z,
                                                    const int2* __restrict__ csr,
                                                    const int* __restrict__ rowstart,
                                                    const float* __restrict__ dinv,
                                                    const float* __restrict__ b4,
                                                    float* __restrict__ out) {
    int i = blockIdx.x * 256 + threadIdx.x;
    if (i >= NN) return;
    float acc = z[i] * dinv[i] * dinv[i] + b4[0];
    int e0 = rowstart[i], e1 = rowstart[i + 1];
    for (int e = e0; e < e1; e++) {
        int2 ed = csr[e];
        acc += z[ed.x] * __int_as_float(ed.y);
    }
    out[i] = acc;
}

// ---------------- launch ----------------

extern "C" void kernel_launch(void* const* d_in, const int* in_sizes, int n_in,
                              void* d_out, int out_size, void* d_ws, size_t ws_size,
                              hipStream_t stream) {
    const float* x   = (const float*)d_in[0];
    const int*   ei  = (const int*)d_in[1];
    const int*   src = ei;
    const int*   dst = ei + EE;
    const float* W1 = (const float*)d_in[2];
    const float* b1 = (const float*)d_in[3];
    const float* g1 = (const float*)d_in[4];
    const float* be1 = (const float*)d_in[5];
    const float* m1 = (const float*)d_in[6];
    const float* v1 = (const float*)d_in[7];
    const float* W2 = (const float*)d_in[8];
    const float* b2 = (const float*)d_in[9];
    const float* g2 = (const float*)d_in[10];
    const float* be2 = (const float*)d_in[11];
    const float* m2 = (const float*)d_in[12];
    const float* v2 = (const float*)d_in[13];
    const float* W3 = (const float*)d_in[14];
    const float* b3 = (const float*)d_in[15];
    const float* g3 = (const float*)d_in[16];
    const float* be3 = (const float*)d_in[17];
    const float* m3 = (const float*)d_in[18];
    const float* v3 = (const float*)d_in[19];
    const float* W4 = (const float*)d_in[20];
    const float* b4 = (const float*)d_in[21];

    char* wp = (char*)d_ws;
    int*   deg      = (int*)wp;                      wp += (size_t)NN * 4;
    int*   blksum   = (int*)wp;                      wp += 512 * 4;
    int*   rowstart = (int*)wp;                      wp += (size_t)(NN + 1) * 4;
    int*   cursor   = (int*)wp;                      wp += (size_t)NN * 4;
    float* dinv     = (float*)wp;                    wp += (size_t)NN * 4;
    int2*  csr      = (int2*)wp;                     wp += (size_t)EE * 8;
    float* z        = (float*)wp;                    wp += (size_t)NN * 4;
    float* x1       = (float*)wp;                    wp += (size_t)NN * HH * 4;
    float* bufA     = (float*)wp;                    wp += (size_t)NN * HH * 4;
    float* bufB     = (float*)wp;                    wp += (size_t)NN * HH * 4;

    float* outp = (float*)d_out;

    // ---- CSR build
    hipMemsetAsync(deg, 0, (size_t)NN * 4, stream);
    hist_kernel<<<(EE + 255) / 256, 256, 0, stream>>>(dst, deg);
    dinv_kernel<<<(NN + 255) / 256, 256, 0, stream>>>(deg, dinv);
    scan1_kernel<<<NB, 256, 0, stream>>>(deg, rowstart, blksum);
    scan2_kernel<<<1, 512, 0, stream>>>(blksum);
    scan3_kernel<<<NB, 256, 0, stream>>>(rowstart, blksum, cursor);
    fill_kernel<<<(EE + 255) / 256, 256, 0, stream>>>(src, dst, dinv, cursor, csr);

    // ---- layer 1: aggregate x (64 feat), then GEMM 64->128 + BN + ReLU
    agg64_kernel<<<(NN + 7) / 8, 256, 0, stream>>>(x, csr, rowstart, dinv, bufA);
    gemm_bn_relu<FIN><<<(NN + 127) / 128, 256, 0, stream>>>(bufA, W1, b1, g1, be1, m1, v1, nullptr, x1);

    // ---- layer 2
    agg128_kernel<<<(NN + 3) / 4, 256, 0, stream>>>(x1, csr, rowstart, dinv, bufA);
    gemm_bn_relu<HH><<<(NN + 127) / 128, 256, 0, stream>>>(bufA, W2, b2, g2, be2, m2, v2, nullptr, bufB);

    // ---- layer 3 (+ residual x1 after relu)
    agg128_kernel<<<(NN + 3) / 4, 256, 0, stream>>>(bufB, csr, rowstart, dinv, bufA);
    gemm_bn_relu<HH><<<(NN + 127) / 128, 256, 0, stream>>>(bufA, W3, b3, g3, be3, m3, v3, x1, bufB);

    // ---- layer 4: GEMV first (128->1), then gather-aggregate scalars
    gemv_kernel<<<(NN + 3) / 4, 256, 0, stream>>>(bufB, W4, z);
    final_kernel<<<(NN + 255) / 256, 256, 0, stream>>>(z, csr, rowstart, dinv, b4, outp);
}

// Round 4
// 364.577 us; speedup vs baseline: 1.2991x; 1.2991x over previous
//
#include <hip/hip_runtime.h>

#define NN 100000
#define EE 500000
#define FIN 64
#define HH 128
#define BN_EPS 1e-5f
#define NB ((NN + 255) / 256)   // 391 scan blocks

typedef short bf16x8 __attribute__((ext_vector_type(8)));
typedef float f32x4 __attribute__((ext_vector_type(4)));

__device__ __forceinline__ unsigned short f2bf(float f) {
    unsigned int u = __float_as_uint(f);
    u = (u + 0x7FFFu + ((u >> 16) & 1u)) >> 16;   // round-to-nearest-even
    return (unsigned short)u;
}

// ---------------- CSR build ----------------

__global__ __launch_bounds__(256) void hist_kernel(const int* __restrict__ dst,
                                                   int* __restrict__ deg) {
    int e = blockIdx.x * 256 + threadIdx.x;
    if (e < EE) atomicAdd(&deg[dst[e]], 1);
}

__global__ __launch_bounds__(256) void dinv_kernel(const int* __restrict__ deg,
                                                   float* __restrict__ dinv) {
    int i = blockIdx.x * 256 + threadIdx.x;
    if (i < NN) dinv[i] = rsqrtf((float)deg[i] + 1.0f);
}

__global__ __launch_bounds__(256) void scan1_kernel(const int* __restrict__ deg,
                                                    int* __restrict__ rowstart,
                                                    int* __restrict__ blksum) {
    __shared__ int s[256];
    int t = threadIdx.x;
    int i = blockIdx.x * 256 + t;
    int v = (i < NN) ? deg[i] : 0;
    s[t] = v;
    __syncthreads();
    #pragma unroll
    for (int off = 1; off < 256; off <<= 1) {
        int add = (t >= off) ? s[t - off] : 0;
        __syncthreads();
        s[t] += add;
        __syncthreads();
    }
    if (i < NN) rowstart[i] = s[t] - v;
    if (t == 255) blksum[blockIdx.x] = s[255];
}

__global__ __launch_bounds__(512) void scan2_kernel(int* __restrict__ blksum) {
    __shared__ int s[512];
    int t = threadIdx.x;
    int v = (t < NB) ? blksum[t] : 0;
    s[t] = v;
    __syncthreads();
    #pragma unroll
    for (int off = 1; off < 512; off <<= 1) {
        int add = (t >= off) ? s[t - off] : 0;
        __syncthreads();
        s[t] += add;
        __syncthreads();
    }
    if (t < NB) blksum[t] = s[t] - v;
}

__global__ __launch_bounds__(256) void scan3_kernel(int* __restrict__ rowstart,
                                                    const int* __restrict__ blksum,
                                                    int* __restrict__ cursor) {
    int i = blockIdx.x * 256 + threadIdx.x;
    if (i < NN) {
        int r = rowstart[i] + blksum[i >> 8];
        rowstart[i] = r;
        cursor[i] = r;
    }
    if (i == 0) rowstart[NN] = EE;
}

__global__ __launch_bounds__(256) void fill_kernel(const int* __restrict__ src,
                                                   const int* __restrict__ dst,
                                                   const float* __restrict__ dinv,
                                                   int* __restrict__ cursor,
                                                   int2* __restrict__ csr) {
    int e = blockIdx.x * 256 + threadIdx.x;
    if (e >= EE) return;
    int s = src[e];
    int d = dst[e];
    float nm = dinv[s] * dinv[d];
    int pos = atomicAdd(&cursor[d], 1);
    csr[pos] = make_int2(s, __float_as_int(nm));
}

// ---------------- gather aggregation ----------------

__global__ __launch_bounds__(256) void agg128_kernel(const float* __restrict__ x,
                                                     const int2* __restrict__ csr,
                                                     const int* __restrict__ rowstart,
                                                     const float* __restrict__ dinv,
                                                     float* __restrict__ out) {
    int gid = blockIdx.x * 4 + (threadIdx.x >> 6);
    int lane = threadIdx.x & 63;
    if (gid >= NN) return;
    float sn = dinv[gid];
    sn *= sn;
    float2 acc = *(const float2*)&x[(size_t)gid * HH + lane * 2];
    acc.x *= sn; acc.y *= sn;
    int e0 = rowstart[gid], e1 = rowstart[gid + 1];
    for (int e = e0; e < e1; e++) {
        int2 ed = csr[e];
        float w = __int_as_float(ed.y);
        float2 xs = *(const float2*)&x[(size_t)ed.x * HH + lane * 2];
        acc.x += xs.x * w;
        acc.y += xs.y * w;
    }
    *(float2*)&out[(size_t)gid * HH + lane * 2] = acc;
}

__global__ __launch_bounds__(256) void agg64_kernel(const float* __restrict__ x,
                                                    const int2* __restrict__ csr,
                                                    const int* __restrict__ rowstart,
                                                    const float* __restrict__ dinv,
                                                    float* __restrict__ out) {
    int gid = blockIdx.x * 8 + (threadIdx.x >> 5);
    int lane = threadIdx.x & 31;
    if (gid >= NN) return;
    float sn = dinv[gid];
    sn *= sn;
    float2 acc = *(const float2*)&x[(size_t)gid * FIN + lane * 2];
    acc.x *= sn; acc.y *= sn;
    int e0 = rowstart[gid], e1 = rowstart[gid + 1];
    for (int e = e0; e < e1; e++) {
        int2 ed = csr[e];
        float w = __int_as_float(ed.y);
        float2 xs = *(const float2*)&x[(size_t)ed.x * FIN + lane * 2];
        acc.x += xs.x * w;
        acc.y += xs.y * w;
    }
    *(float2*)&out[(size_t)gid * FIN + lane * 2] = acc;
}

// ---------------- MFMA GEMM + bias + BN(eval) + ReLU (+ residual) ----------------
// C[N x 128] = A[N x K] @ W[K x 128]; bf16 MFMA 16x16x32, fp32 accumulate.
// Block: 256 thr = 4 waves, BM=128 (wave: 2 row-tiles x 8 col-tiles).
// W transposed -> LDS bf16, XOR-swizzled; A frags straight from global.

template<int K>
__global__ __launch_bounds__(256) void gemm_bn_relu(const float* __restrict__ A,
                                                    const float* __restrict__ W,
                                                    const float* __restrict__ bias,
                                                    const float* __restrict__ g,
                                                    const float* __restrict__ be,
                                                    const float* __restrict__ m,
                                                    const float* __restrict__ v,
                                                    const float* __restrict__ res,
                                                    float* __restrict__ out) {
    __shared__ unsigned short Wt[HH * K];   // Wt[n][k] bf16, swizzled

    int tid = threadIdx.x;

    // ---- stage W^T into LDS as bf16 (8 consecutive k per 16B chunk)
    constexpr int NCHUNK = HH * K / 8;
    #pragma unroll
    for (int c = 0; c < NCHUNK / 256; c++) {
        int id = tid + c * 256;
        int n  = id & 127;
        int k8 = id >> 7;        // octet index: k = k8*8 .. +7
        unsigned int pk[4];
        #pragma unroll
        for (int jp = 0; jp < 4; jp++) {
            unsigned int lo = f2bf(W[(size_t)(k8 * 8 + jp * 2) * HH + n]);
            unsigned int hi = f2bf(W[(size_t)(k8 * 8 + jp * 2 + 1) * HH + n]);
            pk[jp] = lo | (hi << 16);
        }
        int byte = n * (2 * K) + k8 * 16;
        byte ^= (n & 7) << 4;
        *(uint4*)((char*)Wt + byte) = make_uint4(pk[0], pk[1], pk[2], pk[3]);
    }
    __syncthreads();

    int wave = tid >> 6;
    int lane = tid & 63;
    int lrow = lane & 15;        // m-row / n-col within tile
    int kgrp = lane >> 4;        // which 8-k octet within 32

    int r0 = blockIdx.x * 128 + wave * 32;

    f32x4 acc[2][8];
    #pragma unroll
    for (int t = 0; t < 2; t++)
        #pragma unroll
        for (int ct = 0; ct < 8; ct++)
            acc[t][ct] = (f32x4){0.f, 0.f, 0.f, 0.f};

    #pragma unroll
    for (int kc = 0; kc < K / 32; kc++) {
        // A fragments: 8 consecutive fp32 -> 8 bf16
        bf16x8 afr[2];
        #pragma unroll
        for (int t = 0; t < 2; t++) {
            int row = r0 + t * 16 + lrow;
            if (row >= NN) row = NN - 1;
            const float* ap = &A[(size_t)row * K + kc * 32 + kgrp * 8];
            float4 f0 = *(const float4*)ap;
            float4 f1 = *(const float4*)(ap + 4);
            bf16x8 a;
            a[0] = (short)f2bf(f0.x); a[1] = (short)f2bf(f0.y);
            a[2] = (short)f2bf(f0.z); a[3] = (short)f2bf(f0.w);
            a[4] = (short)f2bf(f1.x); a[5] = (short)f2bf(f1.y);
            a[6] = (short)f2bf(f1.z); a[7] = (short)f2bf(f1.w);
            afr[t] = a;
        }
        // B fragments from swizzled LDS
        bf16x8 bfr[8];
        #pragma unroll
        for (int ct = 0; ct < 8; ct++) {
            int n = ct * 16 + lrow;
            int byte = n * (2 * K) + kc * 64 + kgrp * 16;
            byte ^= (n & 7) << 4;
            bfr[ct] = *(bf16x8*)((char*)Wt + byte);
        }
        #pragma unroll
        for (int t = 0; t < 2; t++)
            #pragma unroll
            for (int ct = 0; ct < 8; ct++)
                acc[t][ct] = __builtin_amdgcn_mfma_f32_16x16x32_bf16(
                    afr[t], bfr[ct], acc[t][ct], 0, 0, 0);
    }

    // ---- epilogue: BN scale/shift per column, relu, +res
    float sc[8], sh[8];
    #pragma unroll
    for (int ct = 0; ct < 8; ct++) {
        int col = ct * 16 + lrow;
        float s = g[col] * rsqrtf(v[col] + BN_EPS);
        sc[ct] = s;
        sh[ct] = (bias[col] - m[col]) * s + be[col];
    }
    int rbase = kgrp * 4;
    #pragma unroll
    for (int t = 0; t < 2; t++) {
        #pragma unroll
        for (int r = 0; r < 4; r++) {
            int row = r0 + t * 16 + rbase + r;
            if (row >= NN) continue;
            #pragma unroll
            for (int ct = 0; ct < 8; ct++) {
                float val = acc[t][ct][r] * sc[ct] + sh[ct];
                val = fmaxf(val, 0.0f);
                if (res) val += res[(size_t)row * HH + ct * 16 + lrow];
                out[(size_t)row * HH + ct * 16 + lrow] = val;
            }
        }
    }
}

// ---------------- layer 4: z = x3 @ W4 (128 -> 1) ----------------

__global__ __launch_bounds__(256) void gemv_kernel(const float* __restrict__ x3,
                                                   const float* __restrict__ W4,
                                                   float* __restrict__ z) {
    int gtid = blockIdx.x * 256 + threadIdx.x;
    int row = gtid >> 6;
    int lane = gtid & 63;
    if (row >= NN) return;
    float2 xv = *(const float2*)&x3[(size_t)row * HH + lane * 2];
    float2 wv = *(const float2*)&W4[lane * 2];
    float s = xv.x * wv.x + xv.y * wv.y;
    #pragma unroll
    for (int off = 32; off; off >>= 1) s += __shfl_xor(s, off, 64);
    if (lane == 0) z[row] = s;
}

__global__ __launch_bounds__(256) void final_kernel(const float* __restrict__ z,
                                                    const int2* __restrict__ csr,
                                                    const int* __restrict__ rowstart,
                                                    const float* __restrict__ dinv,
                                                    const float* __restrict__ b4,
                                                    float* __restrict__ out) {
    int i = blockIdx.x * 256 + threadIdx.x;
    if (i >= NN) return;
    float acc = z[i] * dinv[i] * dinv[i] + b4[0];
    int e0 = rowstart[i], e1 = rowstart[i + 1];
    for (int e = e0; e < e1; e++) {
        int2 ed = csr[e];
        acc += z[ed.x] * __int_as_float(ed.y);
    }
    out[i] = acc;
}

// ---------------- launch ----------------

extern "C" void kernel_launch(void* const* d_in, const int* in_sizes, int n_in,
                              void* d_out, int out_size, void* d_ws, size_t ws_size,
                              hipStream_t stream) {
    const float* x   = (const float*)d_in[0];
    const int*   ei  = (const int*)d_in[1];
    const int*   src = ei;
    const int*   dst = ei + EE;
    const float* W1 = (const float*)d_in[2];
    const float* b1 = (const float*)d_in[3];
    const float* g1 = (const float*)d_in[4];
    const float* be1 = (const float*)d_in[5];
    const float* m1 = (const float*)d_in[6];
    const float* v1 = (const float*)d_in[7];
    const float* W2 = (const float*)d_in[8];
    const float* b2 = (const float*)d_in[9];
    const float* g2 = (const float*)d_in[10];
    const float* be2 = (const float*)d_in[11];
    const float* m2 = (const float*)d_in[12];
    const float* v2 = (const float*)d_in[13];
    const float* W3 = (const float*)d_in[14];
    const float* b3 = (const float*)d_in[15];
    const float* g3 = (const float*)d_in[16];
    const float* be3 = (const float*)d_in[17];
    const float* m3 = (const float*)d_in[18];
    const float* v3 = (const float*)d_in[19];
    const float* W4 = (const float*)d_in[20];
    const float* b4 = (const float*)d_in[21];

    char* wp = (char*)d_ws;
    int*   deg      = (int*)wp;                      wp += (size_t)NN * 4;
    int*   blksum   = (int*)wp;                      wp += 512 * 4;
    int*   rowstart = (int*)wp;                      wp += (size_t)(NN + 1) * 4;
    int*   cursor   = (int*)wp;                      wp += (size_t)NN * 4;
    float* dinv     = (float*)wp;                    wp += (size_t)NN * 4;
    int2*  csr      = (int2*)wp;                     wp += (size_t)EE * 8;
    float* z        = (float*)wp;                    wp += (size_t)NN * 4;
    float* x1       = (float*)wp;                    wp += (size_t)NN * HH * 4;
    float* bufA     = (float*)wp;                    wp += (size_t)NN * HH * 4;
    float* bufB     = (float*)wp;                    wp += (size_t)NN * HH * 4;

    float* outp = (float*)d_out;

    // ---- CSR build
    hipMemsetAsync(deg, 0, (size_t)NN * 4, stream);
    hist_kernel<<<(EE + 255) / 256, 256, 0, stream>>>(dst, deg);
    dinv_kernel<<<(NN + 255) / 256, 256, 0, stream>>>(deg, dinv);
    scan1_kernel<<<NB, 256, 0, stream>>>(deg, rowstart, blksum);
    scan2_kernel<<<1, 512, 0, stream>>>(blksum);
    scan3_kernel<<<NB, 256, 0, stream>>>(rowstart, blksum, cursor);
    fill_kernel<<<(EE + 255) / 256, 256, 0, stream>>>(src, dst, dinv, cursor, csr);

    // ---- layer 1: aggregate x (64 feat), then GEMM 64->128 + BN + ReLU
    agg64_kernel<<<(NN + 7) / 8, 256, 0, stream>>>(x, csr, rowstart, dinv, bufA);
    gemm_bn_relu<FIN><<<(NN + 127) / 128, 256, 0, stream>>>(bufA, W1, b1, g1, be1, m1, v1, nullptr, x1);

    // ---- layer 2
    agg128_kernel<<<(NN + 3) / 4, 256, 0, stream>>>(x1, csr, rowstart, dinv, bufA);
    gemm_bn_relu<HH><<<(NN + 127) / 128, 256, 0, stream>>>(bufA, W2, b2, g2, be2, m2, v2, nullptr, bufB);

    // ---- layer 3 (+ residual x1 after relu)
    agg128_kernel<<<(NN + 3) / 4, 256, 0, stream>>>(bufB, csr, rowstart, dinv, bufA);
    gemm_bn_relu<HH><<<(NN + 127) / 128, 256, 0, stream>>>(bufA, W3, b3, g3, be3, m3, v3, x1, bufB);

    // ---- layer 4: GEMV first (128->1), then gather-aggregate scalars
    gemv_kernel<<<(NN + 3) / 4, 256, 0, stream>>>(bufB, W4, z);
    final_kernel<<<(NN + 255) / 256, 256, 0, stream>>>(z, csr, rowstart, dinv, b4, outp);
}

// Round 5
// 330.906 us; speedup vs baseline: 1.4313x; 1.1018x over previous
//
#include <hip/hip_runtime.h>

#define NN 100000
#define EE 500000
#define FIN 64
#define HH 128
#define BN_EPS 1e-5f
#define NB ((NN + 255) / 256)   // 391 scan blocks

typedef unsigned short u16;
typedef short bf16x8 __attribute__((ext_vector_type(8)));
typedef float f32x4 __attribute__((ext_vector_type(4)));

__device__ __forceinline__ u16 f2bf(float f) {
    unsigned int u = __float_as_uint(f);
    u = (u + 0x7FFFu + ((u >> 16) & 1u)) >> 16;   // round-to-nearest-even
    return (u16)u;
}
__device__ __forceinline__ float bf2f(u16 u) {
    return __uint_as_float((unsigned int)u << 16);
}

// ---------------- CSR build ----------------

__global__ __launch_bounds__(256) void hist_kernel(const int* __restrict__ dst,
                                                   int* __restrict__ deg) {
    int e = blockIdx.x * 256 + threadIdx.x;
    if (e < EE) atomicAdd(&deg[dst[e]], 1);
}

__global__ __launch_bounds__(256) void dinv_kernel(const int* __restrict__ deg,
                                                   float* __restrict__ dinv) {
    int i = blockIdx.x * 256 + threadIdx.x;
    if (i < NN) dinv[i] = rsqrtf((float)deg[i] + 1.0f);
}

__global__ __launch_bounds__(256) void scan1_kernel(const int* __restrict__ deg,
                                                    int* __restrict__ rowstart,
                                                    int* __restrict__ blksum) {
    __shared__ int s[256];
    int t = threadIdx.x;
    int i = blockIdx.x * 256 + t;
    int v = (i < NN) ? deg[i] : 0;
    s[t] = v;
    __syncthreads();
    #pragma unroll
    for (int off = 1; off < 256; off <<= 1) {
        int add = (t >= off) ? s[t - off] : 0;
        __syncthreads();
        s[t] += add;
        __syncthreads();
    }
    if (i < NN) rowstart[i] = s[t] - v;
    if (t == 255) blksum[blockIdx.x] = s[255];
}

__global__ __launch_bounds__(512) void scan2_kernel(int* __restrict__ blksum) {
    __shared__ int s[512];
    int t = threadIdx.x;
    int v = (t < NB) ? blksum[t] : 0;
    s[t] = v;
    __syncthreads();
    #pragma unroll
    for (int off = 1; off < 512; off <<= 1) {
        int add = (t >= off) ? s[t - off] : 0;
        __syncthreads();
        s[t] += add;
        __syncthreads();
    }
    if (t < NB) blksum[t] = s[t] - v;
}

__global__ __launch_bounds__(256) void scan3_kernel(int* __restrict__ rowstart,
                                                    const int* __restrict__ blksum,
                                                    int* __restrict__ cursor) {
    int i = blockIdx.x * 256 + threadIdx.x;
    if (i < NN) {
        int r = rowstart[i] + blksum[i >> 8];
        rowstart[i] = r;
        cursor[i] = r;
    }
    if (i == 0) rowstart[NN] = EE;
}

__global__ __launch_bounds__(256) void fill_kernel(const int* __restrict__ src,
                                                   const int* __restrict__ dst,
                                                   const float* __restrict__ dinv,
                                                   int* __restrict__ cursor,
                                                   int2* __restrict__ csr) {
    int e = blockIdx.x * 256 + threadIdx.x;
    if (e >= EE) return;
    int s = src[e];
    int d = dst[e];
    float nm = dinv[s] * dinv[d];
    int pos = atomicAdd(&cursor[d], 1);
    csr[pos] = make_int2(s, __float_as_int(nm));
}

// ---------------- fp32 -> bf16 convert (input features) ----------------

__global__ __launch_bounds__(256) void x2bf_kernel(const float* __restrict__ x,
                                                   u16* __restrict__ xb) {
    int i = blockIdx.x * 256 + threadIdx.x;
    if (i >= NN * FIN / 4) return;
    float4 f = ((const float4*)x)[i];
    uint2 o;
    o.x = (unsigned)f2bf(f.x) | ((unsigned)f2bf(f.y) << 16);
    o.y = (unsigned)f2bf(f.z) | ((unsigned)f2bf(f.w) << 16);
    ((uint2*)xb)[i] = o;
}

// ---------------- gather aggregation (bf16 in/out, fp32 accumulate) ----------------

__global__ __launch_bounds__(256) void agg128_kernel(const u16* __restrict__ x,
                                                     const int2* __restrict__ csr,
                                                     const int* __restrict__ rowstart,
                                                     const float* __restrict__ dinv,
                                                     u16* __restrict__ out) {
    int gid = blockIdx.x * 4 + (threadIdx.x >> 6);
    int lane = threadIdx.x & 63;
    if (gid >= NN) return;
    float sn = dinv[gid];
    sn *= sn;
    const ushort2* xp = (const ushort2*)x;
    ushort2 xv = xp[(size_t)gid * 64 + lane];
    float ax = bf2f(xv.x) * sn, ay = bf2f(xv.y) * sn;
    int e0 = rowstart[gid], e1 = rowstart[gid + 1];
    for (int e = e0; e < e1; e++) {
        int2 ed = csr[e];
        float w = __int_as_float(ed.y);
        ushort2 xs = xp[(size_t)ed.x * 64 + lane];
        ax += bf2f(xs.x) * w;
        ay += bf2f(xs.y) * w;
    }
    unsigned o = (unsigned)f2bf(ax) | ((unsigned)f2bf(ay) << 16);
    ((unsigned*)out)[(size_t)gid * 64 + lane] = o;
}

__global__ __launch_bounds__(256) void agg64_kernel(const u16* __restrict__ x,
                                                    const int2* __restrict__ csr,
                                                    const int* __restrict__ rowstart,
                                                    const float* __restrict__ dinv,
                                                    u16* __restrict__ out) {
    int gid = blockIdx.x * 8 + (threadIdx.x >> 5);
    int lane = threadIdx.x & 31;
    if (gid >= NN) return;
    float sn = dinv[gid];
    sn *= sn;
    const ushort2* xp = (const ushort2*)x;
    ushort2 xv = xp[(size_t)gid * 32 + lane];
    float ax = bf2f(xv.x) * sn, ay = bf2f(xv.y) * sn;
    int e0 = rowstart[gid], e1 = rowstart[gid + 1];
    for (int e = e0; e < e1; e++) {
        int2 ed = csr[e];
        float w = __int_as_float(ed.y);
        ushort2 xs = xp[(size_t)ed.x * 32 + lane];
        ax += bf2f(xs.x) * w;
        ay += bf2f(xs.y) * w;
    }
    unsigned o = (unsigned)f2bf(ax) | ((unsigned)f2bf(ay) << 16);
    ((unsigned*)out)[(size_t)gid * 32 + lane] = o;
}

// ---------------- MFMA GEMM + bias + BN(eval) + ReLU (+ residual) ----------------
// C[N x 128] = A[N x K] @ W[K x 128]; A bf16, W fp32->bf16 in LDS, fp32 accum.
// 256 thr = 4 waves, BM=128 (wave: 2 row-tiles x 8 col-tiles). out bf16.

template<int K>
__global__ __launch_bounds__(256) void gemm_bn_relu(const u16* __restrict__ A,
                                                    const float* __restrict__ W,
                                                    const float* __restrict__ bias,
                                                    const float* __restrict__ g,
                                                    const float* __restrict__ be,
                                                    const float* __restrict__ m,
                                                    const float* __restrict__ v,
                                                    const u16* __restrict__ res,
                                                    u16* __restrict__ out) {
    __shared__ u16 Wt[HH * K];   // Wt[n][k] bf16, XOR-swizzled

    int tid = threadIdx.x;

    constexpr int NCHUNK = HH * K / 8;
    #pragma unroll
    for (int c = 0; c < NCHUNK / 256; c++) {
        int id = tid + c * 256;
        int n  = id & 127;
        int k8 = id >> 7;
        unsigned int pk[4];
        #pragma unroll
        for (int jp = 0; jp < 4; jp++) {
            unsigned int lo = f2bf(W[(size_t)(k8 * 8 + jp * 2) * HH + n]);
            unsigned int hi = f2bf(W[(size_t)(k8 * 8 + jp * 2 + 1) * HH + n]);
            pk[jp] = lo | (hi << 16);
        }
        int byte = n * (2 * K) + k8 * 16;
        byte ^= (n & 7) << 4;
        *(uint4*)((char*)Wt + byte) = make_uint4(pk[0], pk[1], pk[2], pk[3]);
    }
    __syncthreads();

    int wave = tid >> 6;
    int lane = tid & 63;
    int lrow = lane & 15;
    int kgrp = lane >> 4;

    int r0 = blockIdx.x * 128 + wave * 32;

    f32x4 acc[2][8];
    #pragma unroll
    for (int t = 0; t < 2; t++)
        #pragma unroll
        for (int ct = 0; ct < 8; ct++)
            acc[t][ct] = (f32x4){0.f, 0.f, 0.f, 0.f};

    #pragma unroll
    for (int kc = 0; kc < K / 32; kc++) {
        bf16x8 afr[2];
        #pragma unroll
        for (int t = 0; t < 2; t++) {
            int row = r0 + t * 16 + lrow;
            if (row >= NN) row = NN - 1;
            afr[t] = *(const bf16x8*)&A[(size_t)row * K + kc * 32 + kgrp * 8];
        }
        bf16x8 bfr[8];
        #pragma unroll
        for (int ct = 0; ct < 8; ct++) {
            int n = ct * 16 + lrow;
            int byte = n * (2 * K) + kc * 64 + kgrp * 16;
            byte ^= (n & 7) << 4;
            bfr[ct] = *(bf16x8*)((char*)Wt + byte);
        }
        #pragma unroll
        for (int t = 0; t < 2; t++)
            #pragma unroll
            for (int ct = 0; ct < 8; ct++)
                acc[t][ct] = __builtin_amdgcn_mfma_f32_16x16x32_bf16(
                    afr[t], bfr[ct], acc[t][ct], 0, 0, 0);
    }

    float sc[8], sh[8];
    #pragma unroll
    for (int ct = 0; ct < 8; ct++) {
        int col = ct * 16 + lrow;
        float s = g[col] * rsqrtf(v[col] + BN_EPS);
        sc[ct] = s;
        sh[ct] = (bias[col] - m[col]) * s + be[col];
    }
    int rbase = kgrp * 4;
    #pragma unroll
    for (int t = 0; t < 2; t++) {
        #pragma unroll
        for (int r = 0; r < 4; r++) {
            int row = r0 + t * 16 + rbase + r;
            if (row >= NN) continue;
            #pragma unroll
            for (int ct = 0; ct < 8; ct++) {
                float val = acc[t][ct][r] * sc[ct] + sh[ct];
                val = fmaxf(val, 0.0f);
                if (res) val += bf2f(res[(size_t)row * HH + ct * 16 + lrow]);
                out[(size_t)row * HH + ct * 16 + lrow] = f2bf(val);
            }
        }
    }
}

// ---------------- layer 4: z = x3 @ W4 (128 -> 1) ----------------

__global__ __launch_bounds__(256) void gemv_kernel(const u16* __restrict__ x3,
                                                   const float* __restrict__ W4,
                                                   float* __restrict__ z) {
    int gtid = blockIdx.x * 256 + threadIdx.x;
    int row = gtid >> 6;
    int lane = gtid & 63;
    if (row >= NN) return;
    ushort2 xv = ((const ushort2*)x3)[(size_t)row * 64 + lane];
    float2 wv = *(const float2*)&W4[lane * 2];
    float s = bf2f(xv.x) * wv.x + bf2f(xv.y) * wv.y;
    #pragma unroll
    for (int off = 32; off; off >>= 1) s += __shfl_xor(s, off, 64);
    if (lane == 0) z[row] = s;
}

__global__ __launch_bounds__(256) void final_kernel(const float* __restrict__ z,
                                                    const int2* __restrict__ csr,
                                                    const int* __restrict__ rowstart,
                                                    const float* __restrict__ dinv,
                                                    const float* __restrict__ b4,
                                                    float* __restrict__ out) {
    int i = blockIdx.x * 256 + threadIdx.x;
    if (i >= NN) return;
    float acc = z[i] * dinv[i] * dinv[i] + b4[0];
    int e0 = rowstart[i], e1 = rowstart[i + 1];
    for (int e = e0; e < e1; e++) {
        int2 ed = csr[e];
        acc += z[ed.x] * __int_as_float(ed.y);
    }
    out[i] = acc;
}

// ---------------- launch ----------------

extern "C" void kernel_launch(void* const* d_in, const int* in_sizes, int n_in,
                              void* d_out, int out_size, void* d_ws, size_t ws_size,
                              hipStream_t stream) {
    const float* x   = (const float*)d_in[0];
    const int*   ei  = (const int*)d_in[1];
    const int*   src = ei;
    const int*   dst = ei + EE;
    const float* W1 = (const float*)d_in[2];
    const float* b1 = (const float*)d_in[3];
    const float* g1 = (const float*)d_in[4];
    const float* be1 = (const float*)d_in[5];
    const float* m1 = (const float*)d_in[6];
    const float* v1 = (const float*)d_in[7];
    const float* W2 = (const float*)d_in[8];
    const float* b2 = (const float*)d_in[9];
    const float* g2 = (const float*)d_in[10];
    const float* be2 = (const float*)d_in[11];
    const float* m2 = (const float*)d_in[12];
    const float* v2 = (const float*)d_in[13];
    const float* W3 = (const float*)d_in[14];
    const float* b3 = (const float*)d_in[15];
    const float* g3 = (const float*)d_in[16];
    const float* be3 = (const float*)d_in[17];
    const float* m3 = (const float*)d_in[18];
    const float* v3 = (const float*)d_in[19];
    const float* W4 = (const float*)d_in[20];
    const float* b4 = (const float*)d_in[21];

    char* wp = (char*)d_ws;
    int*   deg      = (int*)wp;                      wp += (size_t)NN * 4;
    int*   blksum   = (int*)wp;                      wp += 512 * 4;
    int*   rowstart = (int*)wp;                      wp += (size_t)(NN + 1) * 4;
    int*   cursor   = (int*)wp;                      wp += (size_t)NN * 4;
    float* dinv     = (float*)wp;                    wp += (size_t)NN * 4;
    int2*  csr      = (int2*)wp;                     wp += (size_t)EE * 8;
    float* z        = (float*)wp;                    wp += (size_t)NN * 4;
    u16*   xb       = (u16*)wp;                      wp += (size_t)NN * FIN * 2;
    u16*   x1       = (u16*)wp;                      wp += (size_t)NN * HH * 2;
    u16*   bufA     = (u16*)wp;                      wp += (size_t)NN * HH * 2;
    u16*   bufB     = (u16*)wp;                      wp += (size_t)NN * HH * 2;

    float* outp = (float*)d_out;

    // ---- CSR build (+ bf16 conversion of x)
    hipMemsetAsync(deg, 0, (size_t)NN * 4, stream);
    hist_kernel<<<(EE + 255) / 256, 256, 0, stream>>>(dst, deg);
    x2bf_kernel<<<(NN * FIN / 4 + 255) / 256, 256, 0, stream>>>(x, xb);
    dinv_kernel<<<(NN + 255) / 256, 256, 0, stream>>>(deg, dinv);
    scan1_kernel<<<NB, 256, 0, stream>>>(deg, rowstart, blksum);
    scan2_kernel<<<1, 512, 0, stream>>>(blksum);
    scan3_kernel<<<NB, 256, 0, stream>>>(rowstart, blksum, cursor);
    fill_kernel<<<(EE + 255) / 256, 256, 0, stream>>>(src, dst, dinv, cursor, csr);

    // ---- layer 1: aggregate xb (64 feat), then GEMM 64->128 + BN + ReLU
    agg64_kernel<<<(NN + 7) / 8, 256, 0, stream>>>(xb, csr, rowstart, dinv, bufA);
    gemm_bn_relu<FIN><<<(NN + 127) / 128, 256, 0, stream>>>(bufA, W1, b1, g1, be1, m1, v1, nullptr, x1);

    // ---- layer 2
    agg128_kernel<<<(NN + 3) / 4, 256, 0, stream>>>(x1, csr, rowstart, dinv, bufA);
    gemm_bn_relu<HH><<<(NN + 127) / 128, 256, 0, stream>>>(bufA, W2, b2, g2, be2, m2, v2, nullptr, bufB);

    // ---- layer 3 (+ residual x1 after relu)
    agg128_kernel<<<(NN + 3) / 4, 256, 0, stream>>>(bufB, csr, rowstart, dinv, bufA);
    gemm_bn_relu<HH><<<(NN + 127) / 128, 256, 0, stream>>>(bufA, W3, b3, g3, be3, m3, v3, x1, bufB);

    // ---- layer 4: GEMV first (128->1), then gather-aggregate scalars
    gemv_kernel<<<(NN + 3) / 4, 256, 0, stream>>>(bufB, W4, z);
    final_kernel<<<(NN + 255) / 256, 256, 0, stream>>>(z, csr, rowstart, dinv, b4, outp);
}

// Round 6
// 262.369 us; speedup vs baseline: 1.8052x; 1.2612x over previous
//
#include <hip/hip_runtime.h>

#define NN 100000
#define EE 500000
#define FIN 64
#define HH 128
#define BN_EPS 1e-5f
#define NB ((NN + 255) / 256)   // 391 scan blocks

typedef unsigned short u16;
typedef short bf16x8 __attribute__((ext_vector_type(8)));
typedef float f32x4 __attribute__((ext_vector_type(4)));

__device__ __forceinline__ u16 f2bf(float f) {
    unsigned int u = __float_as_uint(f);
    u = (u + 0x7FFFu + ((u >> 16) & 1u)) >> 16;   // round-to-nearest-even
    return (u16)u;
}
__device__ __forceinline__ float bf2f(u16 u) {
    return __uint_as_float((unsigned int)u << 16);
}

// ---------------- CSR build ----------------

__global__ __launch_bounds__(256) void hist_kernel(const int* __restrict__ dst,
                                                   int* __restrict__ deg) {
    int e = blockIdx.x * 256 + threadIdx.x;
    if (e < EE) atomicAdd(&deg[dst[e]], 1);
}

__global__ __launch_bounds__(256) void dinv_kernel(const int* __restrict__ deg,
                                                   float* __restrict__ dinv) {
    int i = blockIdx.x * 256 + threadIdx.x;
    if (i < NN) dinv[i] = rsqrtf((float)deg[i] + 1.0f);
}

__global__ __launch_bounds__(256) void scan1_kernel(const int* __restrict__ deg,
                                                    int* __restrict__ rowstart,
                                                    int* __restrict__ blksum) {
    __shared__ int s[256];
    int t = threadIdx.x;
    int i = blockIdx.x * 256 + t;
    int v = (i < NN) ? deg[i] : 0;
    s[t] = v;
    __syncthreads();
    #pragma unroll
    for (int off = 1; off < 256; off <<= 1) {
        int add = (t >= off) ? s[t - off] : 0;
        __syncthreads();
        s[t] += add;
        __syncthreads();
    }
    if (i < NN) rowstart[i] = s[t] - v;
    if (t == 255) blksum[blockIdx.x] = s[255];
}

__global__ __launch_bounds__(512) void scan2_kernel(int* __restrict__ blksum) {
    __shared__ int s[512];
    int t = threadIdx.x;
    int v = (t < NB) ? blksum[t] : 0;
    s[t] = v;
    __syncthreads();
    #pragma unroll
    for (int off = 1; off < 512; off <<= 1) {
        int add = (t >= off) ? s[t - off] : 0;
        __syncthreads();
        s[t] += add;
        __syncthreads();
    }
    if (t < NB) blksum[t] = s[t] - v;
}

__global__ __launch_bounds__(256) void scan3_kernel(int* __restrict__ rowstart,
                                                    const int* __restrict__ blksum,
                                                    int* __restrict__ cursor) {
    int i = blockIdx.x * 256 + threadIdx.x;
    if (i < NN) {
        int r = rowstart[i] + blksum[i >> 8];
        rowstart[i] = r;
        cursor[i] = r;
    }
    if (i == 0) rowstart[NN] = EE;
}

__global__ __launch_bounds__(256) void fill_kernel(const int* __restrict__ src,
                                                   const int* __restrict__ dst,
                                                   const float* __restrict__ dinv,
                                                   int* __restrict__ cursor,
                                                   int2* __restrict__ csr) {
    int e = blockIdx.x * 256 + threadIdx.x;
    if (e >= EE) return;
    int s = src[e];
    int d = dst[e];
    float nm = dinv[s] * dinv[d];
    int pos = atomicAdd(&cursor[d], 1);
    csr[pos] = make_int2(s, __float_as_int(nm));
}

// ---------------- fp32 -> bf16 convert (input features) ----------------

__global__ __launch_bounds__(256) void x2bf_kernel(const float* __restrict__ x,
                                                   u16* __restrict__ xb) {
    int i = blockIdx.x * 256 + threadIdx.x;
    if (i >= NN * FIN / 4) return;
    float4 f = ((const float4*)x)[i];
    uint2 o;
    o.x = (unsigned)f2bf(f.x) | ((unsigned)f2bf(f.y) << 16);
    o.y = (unsigned)f2bf(f.z) | ((unsigned)f2bf(f.w) << 16);
    ((uint2*)xb)[i] = o;
}

// ---------------- gather aggregation (bf16 in/out, fp32 accumulate) ----------------
// latency-oriented: sub-wave per node + edge loop unrolled x4 (batched loads)

// 128 feats: 32-lane group per node, ushort4 (8B) per lane
__global__ __launch_bounds__(256) void agg128_kernel(const u16* __restrict__ x,
                                                     const int2* __restrict__ csr,
                                                     const int* __restrict__ rowstart,
                                                     const float* __restrict__ dinv,
                                                     u16* __restrict__ out) {
    int gid = blockIdx.x * 8 + (threadIdx.x >> 5);
    int lane = threadIdx.x & 31;
    if (gid >= NN) return;
    float sn = dinv[gid];
    sn *= sn;
    const ushort4* xp = (const ushort4*)x;   // row = 32 x ushort4
    ushort4 xv = xp[(size_t)gid * 32 + lane];
    float a0 = bf2f(xv.x) * sn, a1 = bf2f(xv.y) * sn;
    float a2 = bf2f(xv.z) * sn, a3 = bf2f(xv.w) * sn;
    int e0 = rowstart[gid], e1 = rowstart[gid + 1];
    int e = e0;
    for (; e + 4 <= e1; e += 4) {
        int2 d0 = csr[e + 0];
        int2 d1 = csr[e + 1];
        int2 d2 = csr[e + 2];
        int2 d3 = csr[e + 3];
        ushort4 s0 = xp[(size_t)d0.x * 32 + lane];
        ushort4 s1 = xp[(size_t)d1.x * 32 + lane];
        ushort4 s2 = xp[(size_t)d2.x * 32 + lane];
        ushort4 s3 = xp[(size_t)d3.x * 32 + lane];
        float w0 = __int_as_float(d0.y), w1 = __int_as_float(d1.y);
        float w2 = __int_as_float(d2.y), w3 = __int_as_float(d3.y);
        a0 += bf2f(s0.x) * w0; a1 += bf2f(s0.y) * w0; a2 += bf2f(s0.z) * w0; a3 += bf2f(s0.w) * w0;
        a0 += bf2f(s1.x) * w1; a1 += bf2f(s1.y) * w1; a2 += bf2f(s1.z) * w1; a3 += bf2f(s1.w) * w1;
        a0 += bf2f(s2.x) * w2; a1 += bf2f(s2.y) * w2; a2 += bf2f(s2.z) * w2; a3 += bf2f(s2.w) * w2;
        a0 += bf2f(s3.x) * w3; a1 += bf2f(s3.y) * w3; a2 += bf2f(s3.z) * w3; a3 += bf2f(s3.w) * w3;
    }
    for (; e < e1; e++) {
        int2 ed = csr[e];
        float w = __int_as_float(ed.y);
        ushort4 xs = xp[(size_t)ed.x * 32 + lane];
        a0 += bf2f(xs.x) * w; a1 += bf2f(xs.y) * w;
        a2 += bf2f(xs.z) * w; a3 += bf2f(xs.w) * w;
    }
    uint2 o;
    o.x = (unsigned)f2bf(a0) | ((unsigned)f2bf(a1) << 16);
    o.y = (unsigned)f2bf(a2) | ((unsigned)f2bf(a3) << 16);
    ((uint2*)out)[(size_t)gid * 32 + lane] = o;
}

// 64 feats: 16-lane group per node, ushort4 per lane
__global__ __launch_bounds__(256) void agg64_kernel(const u16* __restrict__ x,
                                                    const int2* __restrict__ csr,
                                                    const int* __restrict__ rowstart,
                                                    const float* __restrict__ dinv,
                                                    u16* __restrict__ out) {
    int gid = blockIdx.x * 16 + (threadIdx.x >> 4);
    int lane = threadIdx.x & 15;
    if (gid >= NN) return;
    float sn = dinv[gid];
    sn *= sn;
    const ushort4* xp = (const ushort4*)x;   // row = 16 x ushort4
    ushort4 xv = xp[(size_t)gid * 16 + lane];
    float a0 = bf2f(xv.x) * sn, a1 = bf2f(xv.y) * sn;
    float a2 = bf2f(xv.z) * sn, a3 = bf2f(xv.w) * sn;
    int e0 = rowstart[gid], e1 = rowstart[gid + 1];
    int e = e0;
    for (; e + 4 <= e1; e += 4) {
        int2 d0 = csr[e + 0];
        int2 d1 = csr[e + 1];
        int2 d2 = csr[e + 2];
        int2 d3 = csr[e + 3];
        ushort4 s0 = xp[(size_t)d0.x * 16 + lane];
        ushort4 s1 = xp[(size_t)d1.x * 16 + lane];
        ushort4 s2 = xp[(size_t)d2.x * 16 + lane];
        ushort4 s3 = xp[(size_t)d3.x * 16 + lane];
        float w0 = __int_as_float(d0.y), w1 = __int_as_float(d1.y);
        float w2 = __int_as_float(d2.y), w3 = __int_as_float(d3.y);
        a0 += bf2f(s0.x) * w0; a1 += bf2f(s0.y) * w0; a2 += bf2f(s0.z) * w0; a3 += bf2f(s0.w) * w0;
        a0 += bf2f(s1.x) * w1; a1 += bf2f(s1.y) * w1; a2 += bf2f(s1.z) * w1; a3 += bf2f(s1.w) * w1;
        a0 += bf2f(s2.x) * w2; a1 += bf2f(s2.y) * w2; a2 += bf2f(s2.z) * w2; a3 += bf2f(s2.w) * w2;
        a0 += bf2f(s3.x) * w3; a1 += bf2f(s3.y) * w3; a2 += bf2f(s3.z) * w3; a3 += bf2f(s3.w) * w3;
    }
    for (; e < e1; e++) {
        int2 ed = csr[e];
        float w = __int_as_float(ed.y);
        ushort4 xs = xp[(size_t)ed.x * 16 + lane];
        a0 += bf2f(xs.x) * w; a1 += bf2f(xs.y) * w;
        a2 += bf2f(xs.z) * w; a3 += bf2f(xs.w) * w;
    }
    uint2 o;
    o.x = (unsigned)f2bf(a0) | ((unsigned)f2bf(a1) << 16);
    o.y = (unsigned)f2bf(a2) | ((unsigned)f2bf(a3) << 16);
    ((uint2*)out)[(size_t)gid * 16 + lane] = o;
}

// ---------------- MFMA GEMM + bias + BN(eval) + ReLU (+ residual) ----------------

template<int K>
__global__ __launch_bounds__(256) void gemm_bn_relu(const u16* __restrict__ A,
                                                    const float* __restrict__ W,
                                                    const float* __restrict__ bias,
                                                    const float* __restrict__ g,
                                                    const float* __restrict__ be,
                                                    const float* __restrict__ m,
                                                    const float* __restrict__ v,
                                                    const u16* __restrict__ res,
                                                    u16* __restrict__ out) {
    __shared__ u16 Wt[HH * K];   // Wt[n][k] bf16, XOR-swizzled

    int tid = threadIdx.x;

    constexpr int NCHUNK = HH * K / 8;
    #pragma unroll
    for (int c = 0; c < NCHUNK / 256; c++) {
        int id = tid + c * 256;
        int n  = id & 127;
        int k8 = id >> 7;
        unsigned int pk[4];
        #pragma unroll
        for (int jp = 0; jp < 4; jp++) {
            unsigned int lo = f2bf(W[(size_t)(k8 * 8 + jp * 2) * HH + n]);
            unsigned int hi = f2bf(W[(size_t)(k8 * 8 + jp * 2 + 1) * HH + n]);
            pk[jp] = lo | (hi << 16);
        }
        int byte = n * (2 * K) + k8 * 16;
        byte ^= (n & 7) << 4;
        *(uint4*)((char*)Wt + byte) = make_uint4(pk[0], pk[1], pk[2], pk[3]);
    }
    __syncthreads();

    int wave = tid >> 6;
    int lane = tid & 63;
    int lrow = lane & 15;
    int kgrp = lane >> 4;

    int r0 = blockIdx.x * 128 + wave * 32;

    f32x4 acc[2][8];
    #pragma unroll
    for (int t = 0; t < 2; t++)
        #pragma unroll
        for (int ct = 0; ct < 8; ct++)
            acc[t][ct] = (f32x4){0.f, 0.f, 0.f, 0.f};

    #pragma unroll
    for (int kc = 0; kc < K / 32; kc++) {
        bf16x8 afr[2];
        #pragma unroll
        for (int t = 0; t < 2; t++) {
            int row = r0 + t * 16 + lrow;
            if (row >= NN) row = NN - 1;
            afr[t] = *(const bf16x8*)&A[(size_t)row * K + kc * 32 + kgrp * 8];
        }
        bf16x8 bfr[8];
        #pragma unroll
        for (int ct = 0; ct < 8; ct++) {
            int n = ct * 16 + lrow;
            int byte = n * (2 * K) + kc * 64 + kgrp * 16;
            byte ^= (n & 7) << 4;
            bfr[ct] = *(bf16x8*)((char*)Wt + byte);
        }
        #pragma unroll
        for (int t = 0; t < 2; t++)
            #pragma unroll
            for (int ct = 0; ct < 8; ct++)
                acc[t][ct] = __builtin_amdgcn_mfma_f32_16x16x32_bf16(
                    afr[t], bfr[ct], acc[t][ct], 0, 0, 0);
    }

    float sc[8], sh[8];
    #pragma unroll
    for (int ct = 0; ct < 8; ct++) {
        int col = ct * 16 + lrow;
        float s = g[col] * rsqrtf(v[col] + BN_EPS);
        sc[ct] = s;
        sh[ct] = (bias[col] - m[col]) * s + be[col];
    }
    int rbase = kgrp * 4;
    #pragma unroll
    for (int t = 0; t < 2; t++) {
        #pragma unroll
        for (int r = 0; r < 4; r++) {
            int row = r0 + t * 16 + rbase + r;
            if (row >= NN) continue;
            #pragma unroll
            for (int ct = 0; ct < 8; ct++) {
                float val = acc[t][ct][r] * sc[ct] + sh[ct];
                val = fmaxf(val, 0.0f);
                if (res) val += bf2f(res[(size_t)row * HH + ct * 16 + lrow]);
                out[(size_t)row * HH + ct * 16 + lrow] = f2bf(val);
            }
        }
    }
}

// ---------------- layer 4: z = x3 @ W4 (128 -> 1) ----------------

__global__ __launch_bounds__(256) void gemv_kernel(const u16* __restrict__ x3,
                                                   const float* __restrict__ W4,
                                                   float* __restrict__ z) {
    int gtid = blockIdx.x * 256 + threadIdx.x;
    int row = gtid >> 6;
    int lane = gtid & 63;
    if (row >= NN) return;
    ushort2 xv = ((const ushort2*)x3)[(size_t)row * 64 + lane];
    float2 wv = *(const float2*)&W4[lane * 2];
    float s = bf2f(xv.x) * wv.x + bf2f(xv.y) * wv.y;
    #pragma unroll
    for (int off = 32; off; off >>= 1) s += __shfl_xor(s, off, 64);
    if (lane == 0) z[row] = s;
}

__global__ __launch_bounds__(256) void final_kernel(const float* __restrict__ z,
                                                    const int2* __restrict__ csr,
                                                    const int* __restrict__ rowstart,
                                                    const float* __restrict__ dinv,
                                                    const float* __restrict__ b4,
                                                    float* __restrict__ out) {
    int i = blockIdx.x * 256 + threadIdx.x;
    if (i >= NN) return;
    float acc = z[i] * dinv[i] * dinv[i] + b4[0];
    int e0 = rowstart[i], e1 = rowstart[i + 1];
    int e = e0;
    for (; e + 4 <= e1; e += 4) {
        int2 d0 = csr[e + 0];
        int2 d1 = csr[e + 1];
        int2 d2 = csr[e + 2];
        int2 d3 = csr[e + 3];
        float z0 = z[d0.x], z1 = z[d1.x], z2 = z[d2.x], z3 = z[d3.x];
        acc += z0 * __int_as_float(d0.y) + z1 * __int_as_float(d1.y)
             + z2 * __int_as_float(d2.y) + z3 * __int_as_float(d3.y);
    }
    for (; e < e1; e++) {
        int2 ed = csr[e];
        acc += z[ed.x] * __int_as_float(ed.y);
    }
    out[i] = acc;
}

// ---------------- launch ----------------

extern "C" void kernel_launch(void* const* d_in, const int* in_sizes, int n_in,
                              void* d_out, int out_size, void* d_ws, size_t ws_size,
                              hipStream_t stream) {
    const float* x   = (const float*)d_in[0];
    const int*   ei  = (const int*)d_in[1];
    const int*   src = ei;
    const int*   dst = ei + EE;
    const float* W1 = (const float*)d_in[2];
    const float* b1 = (const float*)d_in[3];
    const float* g1 = (const float*)d_in[4];
    const float* be1 = (const float*)d_in[5];
    const float* m1 = (const float*)d_in[6];
    const float* v1 = (const float*)d_in[7];
    const float* W2 = (const float*)d_in[8];
    const float* b2 = (const float*)d_in[9];
    const float* g2 = (const float*)d_in[10];
    const float* be2 = (const float*)d_in[11];
    const float* m2 = (const float*)d_in[12];
    const float* v2 = (const float*)d_in[13];
    const float* W3 = (const float*)d_in[14];
    const float* b3 = (const float*)d_in[15];
    const float* g3 = (const float*)d_in[16];
    const float* be3 = (const float*)d_in[17];
    const float* m3 = (const float*)d_in[18];
    const float* v3 = (const float*)d_in[19];
    const float* W4 = (const float*)d_in[20];
    const float* b4 = (const float*)d_in[21];

    char* wp = (char*)d_ws;
    int*   deg      = (int*)wp;                      wp += (size_t)NN * 4;
    int*   blksum   = (int*)wp;                      wp += 512 * 4;
    int*   rowstart = (int*)wp;                      wp += (size_t)(NN + 1) * 4;
    int*   cursor   = (int*)wp;                      wp += (size_t)NN * 4;
    float* dinv     = (float*)wp;                    wp += (size_t)NN * 4;
    int2*  csr      = (int2*)wp;                     wp += (size_t)EE * 8;
    float* z        = (float*)wp;                    wp += (size_t)NN * 4;
    u16*   xb       = (u16*)wp;                      wp += (size_t)NN * FIN * 2;
    u16*   x1       = (u16*)wp;                      wp += (size_t)NN * HH * 2;
    u16*   bufA     = (u16*)wp;                      wp += (size_t)NN * HH * 2;
    u16*   bufB     = (u16*)wp;                      wp += (size_t)NN * HH * 2;

    float* outp = (float*)d_out;

    // ---- CSR build (+ bf16 conversion of x)
    hipMemsetAsync(deg, 0, (size_t)NN * 4, stream);
    hist_kernel<<<(EE + 255) / 256, 256, 0, stream>>>(dst, deg);
    x2bf_kernel<<<(NN * FIN / 4 + 255) / 256, 256, 0, stream>>>(x, xb);
    dinv_kernel<<<(NN + 255) / 256, 256, 0, stream>>>(deg, dinv);
    scan1_kernel<<<NB, 256, 0, stream>>>(deg, rowstart, blksum);
    scan2_kernel<<<1, 512, 0, stream>>>(blksum);
    scan3_kernel<<<NB, 256, 0, stream>>>(rowstart, blksum, cursor);
    fill_kernel<<<(EE + 255) / 256, 256, 0, stream>>>(src, dst, dinv, cursor, csr);

    // ---- layer 1: aggregate xb (64 feat), then GEMM 64->128 + BN + ReLU
    agg64_kernel<<<(NN + 15) / 16, 256, 0, stream>>>(xb, csr, rowstart, dinv, bufA);
    gemm_bn_relu<FIN><<<(NN + 127) / 128, 256, 0, stream>>>(bufA, W1, b1, g1, be1, m1, v1, nullptr, x1);

    // ---- layer 2
    agg128_kernel<<<(NN + 7) / 8, 256, 0, stream>>>(x1, csr, rowstart, dinv, bufA);
    gemm_bn_relu<HH><<<(NN + 127) / 128, 256, 0, stream>>>(bufA, W2, b2, g2, be2, m2, v2, nullptr, bufB);

    // ---- layer 3 (+ residual x1 after relu)
    agg128_kernel<<<(NN + 7) / 8, 256, 0, stream>>>(bufB, csr, rowstart, dinv, bufA);
    gemm_bn_relu<HH><<<(NN + 127) / 128, 256, 0, stream>>>(bufA, W3, b3, g3, be3, m3, v3, x1, bufB);

    // ---- layer 4: GEMV first (128->1), then gather-aggregate scalars
    gemv_kernel<<<(NN + 3) / 4, 256, 0, stream>>>(bufB, W4, z);
    final_kernel<<<(NN + 255) / 256, 256, 0, stream>>>(z, csr, rowstart, dinv, b4, outp);
}